// Round 5
// baseline (340.402 us; speedup 1.0000x reference)
//
#include <hip/hip_runtime.h>

#define NODES 50000
#define CH 128
#define ELLW 64

using frag_ab = __attribute__((ext_vector_type(8))) short;   // 8 bf16
using frag_cd = __attribute__((ext_vector_type(4))) float;   // 4 fp32

__device__ __forceinline__ float bf2f(ushort u) {
    union { unsigned u; float f; } v; v.u = ((unsigned)u) << 16; return v.f;
}
__device__ __forceinline__ ushort f2bf(float f) {
    union { float f; unsigned u; } v; v.f = f;
    unsigned r = v.u + 0x7fff + ((v.u >> 16) & 1);   // RNE
    return (ushort)(r >> 16);
}

// ---------------- prep: 5 weight transposes + deg zeroing (stride-16 counters) ------------
__global__ void prep_weights(const float* __restrict__ Wlin,
                             const float* __restrict__ W1l, const float* __restrict__ W1r,
                             const float* __restrict__ W2l, const float* __restrict__ W2r,
                             ushort* __restrict__ o0, ushort* __restrict__ o1,
                             ushort* __restrict__ o2, ushort* __restrict__ o3,
                             ushort* __restrict__ o4, int* __restrict__ degs) {
    int b = blockIdx.x;
    if (b >= 448) {
        int i = (b - 448) * 256 + threadIdx.y * 128 + threadIdx.x;
        if (i < NODES) degs[i << 4] = 0;   // one counter per 64B line: kills RMW line contention
        return;
    }
    const float* W; ushort* O; int K; int kb;
    if (b < 192) { W = Wlin; O = o0; K = 384; kb = b; }
    else {
        int j = (b - 192) >> 6; kb = (b - 192) & 63; K = 128;
        W = (j == 0) ? W1l : (j == 1) ? W1r : (j == 2) ? W2l : W2r;
        O = (j == 0) ? o1  : (j == 1) ? o2  : (j == 2) ? o3  : o4;
    }
    int k = kb * 2 + threadIdx.y;
    int n = threadIdx.x;
    if (k < K) O[(size_t)n * K + k] = f2bf(W[(size_t)k * 128 + n]);
}

// ---------------- merged: gemm_lin 128-row tiles (blocks < GB) + fill_ell ----------------
__global__ __launch_bounds__(256) void lin_and_ell(
    const float* __restrict__ A, const ushort* __restrict__ Wt,
    const float* __restrict__ bias, ushort* __restrict__ out, int N, int GB,
    const int* __restrict__ ei, int E, int* __restrict__ degs, ushort* __restrict__ ell)
{
    __shared__ ushort As[128 * 32];
    __shared__ ushort Bs[128 * 32];
    if (blockIdx.x >= GB) {
        int e0 = ((blockIdx.x - GB) * 256 + threadIdx.x) * 4;
        if (e0 >= E) return;
        int s[4], dd[4], cnt;
        if (((E & 3) == 0) && (e0 + 3 < E)) {
            int4 sv = *(const int4*)(ei + e0);
            int4 dv = *(const int4*)(ei + E + e0);
            s[0] = sv.x; s[1] = sv.y; s[2] = sv.z; s[3] = sv.w;
            dd[0] = dv.x; dd[1] = dv.y; dd[2] = dv.z; dd[3] = dv.w;
            cnt = 4;
        } else {
            cnt = E - e0; if (cnt > 4) cnt = 4;
#pragma unroll
            for (int j = 0; j < 4; ++j) {
                int e = (j < cnt) ? e0 + j : e0;
                s[j] = ei[e]; dd[j] = ei[E + e];
            }
        }
#pragma unroll
        for (int j = 0; j < 4; ++j) {
            if (j < cnt) {
                int pos = atomicAdd(&degs[dd[j] << 4], 1);
                if (pos < ELLW) ell[(size_t)dd[j] * ELLW + pos] = (ushort)s[j];
            }
        }
        return;
    }
    const int tid = threadIdx.x;
    const int lane = tid & 63;
    const int wave = tid >> 6;
    const int wr = wave >> 1, wc = wave & 1;
    const int row0 = blockIdx.x * 128;
    const int l15 = lane & 15, quad = lane >> 4;

    frag_cd acc[4][4];
#pragma unroll
    for (int i = 0; i < 4; ++i)
#pragma unroll
        for (int j = 0; j < 4; ++j) acc[i][j] = (frag_cd){0.f, 0.f, 0.f, 0.f};

#pragma unroll 1
    for (int k0 = 0; k0 < 384; k0 += 32) {
        __syncthreads();
#pragma unroll
        for (int i = 0; i < 4; ++i) {
            int e = i * 256 + tid;
            int r = e >> 3, q = e & 7;
            int gr = row0 + r; if (gr > N - 1) gr = N - 1;
            float4 v = *(const float4*)(A + (size_t)gr * 384 + k0 + q * 4);
            ushort4 o; o.x = f2bf(v.x); o.y = f2bf(v.y); o.z = f2bf(v.z); o.w = f2bf(v.w);
            *(ushort4*)(As + r * 32 + q * 4) = o;
        }
#pragma unroll
        for (int i = 0; i < 2; ++i) {
            int e = i * 256 + tid;
            uint4 v = *(const uint4*)(Wt + (size_t)(e >> 2) * 384 + k0 + (e & 3) * 8);
            *(uint4*)(Bs + e * 8) = v;
        }
        __syncthreads();

        frag_ab a[4], b[4];
#pragma unroll
        for (int i = 0; i < 4; ++i)
            a[i] = *(const frag_ab*)(As + (wr * 64 + i * 16 + l15) * 32 + quad * 8);
#pragma unroll
        for (int j = 0; j < 4; ++j)
            b[j] = *(const frag_ab*)(Bs + (wc * 64 + j * 16 + l15) * 32 + quad * 8);
#pragma unroll
        for (int i = 0; i < 4; ++i)
#pragma unroll
            for (int j = 0; j < 4; ++j)
                acc[i][j] = __builtin_amdgcn_mfma_f32_16x16x32_bf16(a[i], b[j], acc[i][j], 0, 0, 0);
    }

#pragma unroll
    for (int i = 0; i < 4; ++i)
#pragma unroll
        for (int r = 0; r < 4; ++r) {
            int row = row0 + wr * 64 + i * 16 + quad * 4 + r;
            if (row < N)
#pragma unroll
                for (int j = 0; j < 4; ++j) {
                    int col = wc * 64 + j * 16 + l15;
                    out[(size_t)row * 128 + col] = f2bf(acc[i][j][r] + bias[col]);
                }
        }
}

// ---------------- helpers ----------------
__device__ __forceinline__ void acc8(float* acc, uint4 v) {
    acc[0] += bf2f((ushort)(v.x & 0xffff)); acc[1] += bf2f((ushort)(v.x >> 16));
    acc[2] += bf2f((ushort)(v.y & 0xffff)); acc[3] += bf2f((ushort)(v.y >> 16));
    acc[4] += bf2f((ushort)(v.z & 0xffff)); acc[5] += bf2f((ushort)(v.z >> 16));
    acc[6] += bf2f((ushort)(v.w & 0xffff)); acc[7] += bf2f((ushort)(v.w >> 16));
}

// ---------------- fused: ELL mean-aggregate + dual GEMM, resident weights ---------------
// LDS: Ms 16KB (mean tile, resident) + As 4KB (h k-slice) + Bs 32KB (weight part,
// staged ONCE per part — FULL 2048 chunks, 8x256). Part-0 GEMM has zero internal
// barriers; 11 barriers total vs 16. Bs staging issued before gather to overlap.
template <bool RELU>
__global__ __launch_bounds__(256) void agg_gemm2(
    const ushort* __restrict__ h, const ushort* __restrict__ ell,
    const int* __restrict__ degs,
    const ushort* __restrict__ Wtl, const ushort* __restrict__ Wtr,
    const float* __restrict__ bias, ushort* __restrict__ out, int N)
{
    __shared__ ushort Ms[64 * 128];   // chunk c of row r stored at c ^ (r&7)
    __shared__ ushort As[64 * 32];    // chunk swizzle kq ^ (r&3)
    __shared__ ushort Bs[128 * 128];  // chunk c of row br stored at c ^ (br&7)
    const int tid = threadIdx.x;
    const int lane = tid & 63;
    const int wave = tid >> 6;
    const int row0 = blockIdx.x * 64;
    const int g = lane >> 4;
    const int q = lane & 15;

    // stage Bs <- Wtl first: coalesced loads fly while the gather's dependent loads run
#pragma unroll
    for (int i = 0; i < 8; ++i) {
        int e = i * 256 + tid;           // chunk slot 0..2047 (128 rows x 16 chunks)
        int br = e >> 4, c = e & 15;
        uint4 v = *(const uint4*)(Wtl + (size_t)br * 128 + c * 8);
        *(uint4*)(Bs + br * 128 + ((c ^ (br & 7)) * 8)) = v;
    }

    // gather -> Ms (one node per 16-lane group, 4 iterations)
#pragma unroll 1
    for (int it = 0; it < 4; ++it) {
        int r = (wave << 4) + (it << 2) + g;
        int node = row0 + r;
        int nd = node < N ? node : N - 1;
        const ushort* erow = ell + (size_t)nd * ELLW;
        int d = degs[nd << 4];
        int dc = d < ELLW ? d : ELLW;
        float acc[8];
#pragma unroll
        for (int k = 0; k < 8; ++k) acc[k] = 0.f;
        int n = 0;
        for (; n + 4 <= dc; n += 4) {
            ushort4 iv = *(const ushort4*)(erow + n);
            uint4 v0 = *(const uint4*)(h + (size_t)iv.x * CH + q * 8);
            uint4 v1 = *(const uint4*)(h + (size_t)iv.y * CH + q * 8);
            uint4 v2 = *(const uint4*)(h + (size_t)iv.z * CH + q * 8);
            uint4 v3 = *(const uint4*)(h + (size_t)iv.w * CH + q * 8);
            acc8(acc, v0); acc8(acc, v1); acc8(acc, v2); acc8(acc, v3);
        }
        for (; n < dc; ++n) {
            uint4 v0 = *(const uint4*)(h + (size_t)erow[n] * CH + q * 8);
            acc8(acc, v0);
        }
        float inv = 1.f / fmaxf((float)d, 1.f);
        uint4 o;
        o.x = ((uint)f2bf(acc[1] * inv) << 16) | (uint)f2bf(acc[0] * inv);
        o.y = ((uint)f2bf(acc[3] * inv) << 16) | (uint)f2bf(acc[2] * inv);
        o.z = ((uint)f2bf(acc[5] * inv) << 16) | (uint)f2bf(acc[4] * inv);
        o.w = ((uint)f2bf(acc[7] * inv) << 16) | (uint)f2bf(acc[6] * inv);
        int chunk = q ^ (r & 7);
        *(uint4*)(Ms + r * 128 + chunk * 8) = o;
    }
    __syncthreads();

    const int wr = wave >> 1, wc = wave & 1;
    const int l15 = q, quad = g;

    frag_cd acc2[2][4];
#pragma unroll
    for (int i = 0; i < 2; ++i)
#pragma unroll
        for (int j = 0; j < 4; ++j) acc2[i][j] = (frag_cd){0.f, 0.f, 0.f, 0.f};

    // part 0: mean @ Wtl — all operands LDS-resident, no barriers
#pragma unroll 1
    for (int k0 = 0; k0 < 128; k0 += 32) {
        frag_ab a[2], b[4];
#pragma unroll
        for (int i = 0; i < 2; ++i) {
            int ar = wr * 32 + i * 16 + l15;
            int c = ((k0 >> 3) + quad) ^ (ar & 7);
            a[i] = *(const frag_ab*)(Ms + ar * 128 + c * 8);
        }
#pragma unroll
        for (int j = 0; j < 4; ++j) {
            int br = wc * 64 + j * 16 + l15;
            int c = ((k0 >> 3) + quad) ^ (br & 7);
            b[j] = *(const frag_ab*)(Bs + br * 128 + c * 8);
        }
#pragma unroll
        for (int i = 0; i < 2; ++i)
#pragma unroll
            for (int j = 0; j < 4; ++j)
                acc2[i][j] = __builtin_amdgcn_mfma_f32_16x16x32_bf16(a[i], b[j], acc2[i][j], 0, 0, 0);
    }
    __syncthreads();                       // all waves done reading Bs(Wtl)

    // restage Bs <- Wtr (full 2048 chunks)
#pragma unroll
    for (int i = 0; i < 8; ++i) {
        int e = i * 256 + tid;
        int br = e >> 4, c = e & 15;
        uint4 v = *(const uint4*)(Wtr + (size_t)br * 128 + c * 8);
        *(uint4*)(Bs + br * 128 + ((c ^ (br & 7)) * 8)) = v;
    }

    // part 1: h @ Wtr — As k-slices staged per step
#pragma unroll 1
    for (int k0 = 0; k0 < 128; k0 += 32) {
        int r = tid >> 2, kq = tid & 3;
        int gr = row0 + r; if (gr > N - 1) gr = N - 1;
        uint4 v = *(const uint4*)(h + (size_t)gr * CH + k0 + kq * 8);
        __syncthreads();                   // prev As reads done; 1st iter: Bs(Wtr) visible
        *(uint4*)(As + r * 32 + ((kq ^ (r & 3)) * 8)) = v;
        __syncthreads();

        frag_ab a[2], b[4];
#pragma unroll
        for (int i = 0; i < 2; ++i) {
            int ar = wr * 32 + i * 16 + l15;
            a[i] = *(const frag_ab*)(As + ar * 32 + ((quad ^ (ar & 3)) * 8));
        }
#pragma unroll
        for (int j = 0; j < 4; ++j) {
            int br = wc * 64 + j * 16 + l15;
            int c = ((k0 >> 3) + quad) ^ (br & 7);
            b[j] = *(const frag_ab*)(Bs + br * 128 + c * 8);
        }
#pragma unroll
        for (int i = 0; i < 2; ++i)
#pragma unroll
            for (int j = 0; j < 4; ++j)
                acc2[i][j] = __builtin_amdgcn_mfma_f32_16x16x32_bf16(a[i], b[j], acc2[i][j], 0, 0, 0);
    }

#pragma unroll
    for (int i = 0; i < 2; ++i)
#pragma unroll
        for (int rr = 0; rr < 4; ++rr) {
            int row = row0 + wr * 32 + i * 16 + quad * 4 + rr;
            if (row < N)
#pragma unroll
                for (int j = 0; j < 4; ++j) {
                    int col = wc * 64 + j * 16 + l15;
                    float v = acc2[i][j][rr] + bias[col];
                    if (RELU) v = fmaxf(v, 0.f);
                    out[(size_t)row * 128 + col] = f2bf(v);
                }
        }
}

// ---------------- classifier: 8 edges / 16-lane group ----------------
__device__ __forceinline__ float dot8(uint4 va, uint4 vb) {
    float p = 0.f;
    p += bf2f((ushort)(va.x & 0xffff)) * bf2f((ushort)(vb.x & 0xffff));
    p += bf2f((ushort)(va.x >> 16))    * bf2f((ushort)(vb.x >> 16));
    p += bf2f((ushort)(va.y & 0xffff)) * bf2f((ushort)(vb.y & 0xffff));
    p += bf2f((ushort)(va.y >> 16))    * bf2f((ushort)(vb.y >> 16));
    p += bf2f((ushort)(va.z & 0xffff)) * bf2f((ushort)(vb.z & 0xffff));
    p += bf2f((ushort)(va.z >> 16))    * bf2f((ushort)(vb.z >> 16));
    p += bf2f((ushort)(va.w & 0xffff)) * bf2f((ushort)(vb.w & 0xffff));
    p += bf2f((ushort)(va.w >> 16))    * bf2f((ushort)(vb.w >> 16));
    return p;
}

__global__ __launch_bounds__(256) void classify_bf(
    const ushort* __restrict__ h2, const int* __restrict__ eli,
    int EL, float* __restrict__ out) {
    int gt = blockIdx.x * blockDim.x + threadIdx.x;
    int g0 = (gt >> 4) * 8;
    int lane = gt & 15;
    if (g0 >= EL) return;
    bool full = (g0 + 7 < EL);
    int ha[8], ta[8];
    if (full) {
        int4 h0 = *(const int4*)(eli + g0);
        int4 h1 = *(const int4*)(eli + g0 + 4);
        int4 t0 = *(const int4*)(eli + EL + g0);
        int4 t1 = *(const int4*)(eli + EL + g0 + 4);
        ha[0] = h0.x; ha[1] = h0.y; ha[2] = h0.z; ha[3] = h0.w;
        ha[4] = h1.x; ha[5] = h1.y; ha[6] = h1.z; ha[7] = h1.w;
        ta[0] = t0.x; ta[1] = t0.y; ta[2] = t0.z; ta[3] = t0.w;
        ta[4] = t1.x; ta[5] = t1.y; ta[6] = t1.z; ta[7] = t1.w;
    } else {
#pragma unroll
        for (int j = 0; j < 8; ++j) {
            int gj = (g0 + j < EL) ? g0 + j : EL - 1;
            ha[j] = eli[gj];
            ta[j] = eli[EL + gj];
        }
    }
    uint4 va[8], vb[8];
#pragma unroll
    for (int j = 0; j < 8; ++j) {
        va[j] = *((const uint4*)(h2 + (size_t)ha[j] * CH) + lane);
        vb[j] = *((const uint4*)(h2 + (size_t)ta[j] * CH) + lane);
    }
    float p[8];
#pragma unroll
    for (int j = 0; j < 8; ++j) p[j] = dot8(va[j], vb[j]);
#pragma unroll
    for (int s = 8; s >= 1; s >>= 1) {
#pragma unroll
        for (int j = 0; j < 8; ++j) p[j] += __shfl_down(p[j], s, 16);
    }
    if (lane == 0) {
        if (full) {
            *(float4*)(out + g0)     = make_float4(p[0], p[1], p[2], p[3]);
            *(float4*)(out + g0 + 4) = make_float4(p[4], p[5], p[6], p[7]);
        } else {
#pragma unroll
            for (int j = 0; j < 8; ++j)
                if (g0 + j < EL) out[g0 + j] = p[j];
        }
    }
}

extern "C" void kernel_launch(void* const* d_in, const int* in_sizes, int n_in,
                              void* d_out, int out_size, void* d_ws, size_t ws_size,
                              hipStream_t stream) {
    const float* x     = (const float*)d_in[0];
    const int*   ei    = (const int*)d_in[1];
    const int*   eli   = (const int*)d_in[2];
    const float* W_lin = (const float*)d_in[3];
    const float* b_lin = (const float*)d_in[4];
    const float* W1l   = (const float*)d_in[5];
    const float* b1    = (const float*)d_in[6];
    const float* W1r   = (const float*)d_in[7];
    const float* W2l   = (const float*)d_in[8];
    const float* b2    = (const float*)d_in[9];
    const float* W2r   = (const float*)d_in[10];
    float* out = (float*)d_out;

    const int E  = in_sizes[1] / 2;
    const int EL = in_sizes[2] / 2;
    const int N  = NODES;

    char* ws = (char*)d_ws;
    size_t off = 0;
    auto alloc = [&](size_t bytes) -> void* {
        void* p = ws + off;
        off += (bytes + 255) & ~(size_t)255;
        return p;
    };
    ushort* n0    = (ushort*)alloc((size_t)N * CH * sizeof(ushort));  // h0
    ushort* n1    = (ushort*)alloc((size_t)N * CH * sizeof(ushort));  // h2
    ushort* n2    = (ushort*)alloc((size_t)N * CH * sizeof(ushort));  // h1
    ushort* WtLin = (ushort*)alloc((size_t)CH * 384 * sizeof(ushort));
    ushort* Wt1l  = (ushort*)alloc((size_t)CH * CH * sizeof(ushort));
    ushort* Wt1r  = (ushort*)alloc((size_t)CH * CH * sizeof(ushort));
    ushort* Wt2l  = (ushort*)alloc((size_t)CH * CH * sizeof(ushort));
    ushort* Wt2r  = (ushort*)alloc((size_t)CH * CH * sizeof(ushort));
    int* degs = (int*)alloc((size_t)N * 16 * sizeof(int));  // stride-16: 1 counter / 64B line
    ushort* ell = (ushort*)alloc((size_t)N * ELLW * sizeof(ushort));
    (void)ws_size; (void)n_in; (void)out_size;

    const int GB128 = (N + 127) / 128;          // 391 gemm tiles
    const int EB4   = (E + 1023) / 1024;        // 782 fill blocks (256 thr x 4 edges)
    const int AB64  = (N + 63) / 64;            // 782 fused agg_gemm blocks

    // 1) weight transposes + deg zeroing
    prep_weights<<<dim3(644), dim3(128, 2), 0, stream>>>(
        W_lin, W1l, W1r, W2l, W2r, WtLin, Wt1l, Wt1r, Wt2l, Wt2r, degs);

    // 2) h0 = bf16(x)@W_lin + b_lin  OVERLAPPED WITH  ELL build
    lin_and_ell<<<dim3(GB128 + EB4), dim3(256), 0, stream>>>(
        x, WtLin, b_lin, n0, N, GB128, ei, E, degs, ell);

    // 3) layer 1 fused: h1 = relu(mean(h0)@W1l + h0@W1r + b1) -> n2
    agg_gemm2<true><<<dim3(AB64), dim3(256), 0, stream>>>(
        n0, ell, degs, Wt1l, Wt1r, b1, n2, N);

    // 4) layer 2 fused: h2 = mean(h1)@W2l + h1@W2r + b2 -> n1
    agg_gemm2<false><<<dim3(AB64), dim3(256), 0, stream>>>(
        n2, ell, degs, Wt2l, Wt2r, b2, n1, N);

    // 5) classifier on h2 = n1
    long long groups = ((long long)EL + 7) / 8;
    long long cls_threads = groups * 16;
    classify_bf<<<dim3((int)((cls_threads + 255) / 256)), dim3(256), 0, stream>>>(
        n1, eli, EL, out);
}

// Round 6
// 299.855 us; speedup vs baseline: 1.1352x; 1.1352x over previous
//
#include <hip/hip_runtime.h>

#define NODES 50000
#define CH 128
#define ELLW 64

using frag_ab = __attribute__((ext_vector_type(8))) short;   // 8 bf16
using frag_cd = __attribute__((ext_vector_type(4))) float;   // 4 fp32

__device__ __forceinline__ float bf2f(ushort u) {
    union { unsigned u; float f; } v; v.u = ((unsigned)u) << 16; return v.f;
}
__device__ __forceinline__ ushort f2bf(float f) {
    union { float f; unsigned u; } v; v.f = f;
    unsigned r = v.u + 0x7fff + ((v.u >> 16) & 1);   // RNE
    return (ushort)(r >> 16);
}

// ---------------- prep: 5 weight transposes + deg zeroing (stride-16 counters) ------------
__global__ void prep_weights(const float* __restrict__ Wlin,
                             const float* __restrict__ W1l, const float* __restrict__ W1r,
                             const float* __restrict__ W2l, const float* __restrict__ W2r,
                             ushort* __restrict__ o0, ushort* __restrict__ o1,
                             ushort* __restrict__ o2, ushort* __restrict__ o3,
                             ushort* __restrict__ o4, int* __restrict__ degs) {
    int b = blockIdx.x;
    if (b >= 448) {
        int i = (b - 448) * 256 + threadIdx.y * 128 + threadIdx.x;
        if (i < NODES) degs[i << 4] = 0;
        return;
    }
    const float* W; ushort* O; int K; int kb;
    if (b < 192) { W = Wlin; O = o0; K = 384; kb = b; }
    else {
        int j = (b - 192) >> 6; kb = (b - 192) & 63; K = 128;
        W = (j == 0) ? W1l : (j == 1) ? W1r : (j == 2) ? W2l : W2r;
        O = (j == 0) ? o1  : (j == 1) ? o2  : (j == 2) ? o3  : o4;
    }
    int k = kb * 2 + threadIdx.y;
    int n = threadIdx.x;
    if (k < K) O[(size_t)n * K + k] = f2bf(W[(size_t)k * 128 + n]);
}

// ---------------- merged: gemm_lin 128-row tiles (blocks < GB) + fill_ell ----------------
// Fill role is at its atomic-issue floor (~55us): ushort ELL / 4-edge ILP / line-spread
// counters all neutral (rounds 1,2,5). GEMM role hides under it.
__global__ __launch_bounds__(256) void lin_and_ell(
    const float* __restrict__ A, const ushort* __restrict__ Wt,
    const float* __restrict__ bias, ushort* __restrict__ out, int N, int GB,
    const int* __restrict__ ei, int E, int* __restrict__ degs, ushort* __restrict__ ell)
{
    __shared__ ushort As[128 * 32];
    __shared__ ushort Bs[128 * 32];
    if (blockIdx.x >= GB) {
        int e0 = ((blockIdx.x - GB) * 256 + threadIdx.x) * 4;
        if (e0 >= E) return;
        int s[4], dd[4], cnt;
        if (((E & 3) == 0) && (e0 + 3 < E)) {
            int4 sv = *(const int4*)(ei + e0);
            int4 dv = *(const int4*)(ei + E + e0);
            s[0] = sv.x; s[1] = sv.y; s[2] = sv.z; s[3] = sv.w;
            dd[0] = dv.x; dd[1] = dv.y; dd[2] = dv.z; dd[3] = dv.w;
            cnt = 4;
        } else {
            cnt = E - e0; if (cnt > 4) cnt = 4;
#pragma unroll
            for (int j = 0; j < 4; ++j) {
                int e = (j < cnt) ? e0 + j : e0;
                s[j] = ei[e]; dd[j] = ei[E + e];
            }
        }
#pragma unroll
        for (int j = 0; j < 4; ++j) {
            if (j < cnt) {
                int pos = atomicAdd(&degs[dd[j] << 4], 1);
                if (pos < ELLW) ell[(size_t)dd[j] * ELLW + pos] = (ushort)s[j];
            }
        }
        return;
    }
    const int tid = threadIdx.x;
    const int lane = tid & 63;
    const int wave = tid >> 6;
    const int wr = wave >> 1, wc = wave & 1;
    const int row0 = blockIdx.x * 128;
    const int l15 = lane & 15, quad = lane >> 4;

    frag_cd acc[4][4];
#pragma unroll
    for (int i = 0; i < 4; ++i)
#pragma unroll
        for (int j = 0; j < 4; ++j) acc[i][j] = (frag_cd){0.f, 0.f, 0.f, 0.f};

#pragma unroll 1
    for (int k0 = 0; k0 < 384; k0 += 32) {
        __syncthreads();
#pragma unroll
        for (int i = 0; i < 4; ++i) {
            int e = i * 256 + tid;
            int r = e >> 3, q = e & 7;
            int gr = row0 + r; if (gr > N - 1) gr = N - 1;
            float4 v = *(const float4*)(A + (size_t)gr * 384 + k0 + q * 4);
            ushort4 o; o.x = f2bf(v.x); o.y = f2bf(v.y); o.z = f2bf(v.z); o.w = f2bf(v.w);
            *(ushort4*)(As + r * 32 + q * 4) = o;
        }
#pragma unroll
        for (int i = 0; i < 2; ++i) {
            int e = i * 256 + tid;
            uint4 v = *(const uint4*)(Wt + (size_t)(e >> 2) * 384 + k0 + (e & 3) * 8);
            *(uint4*)(Bs + e * 8) = v;
        }
        __syncthreads();

        frag_ab a[4], b[4];
#pragma unroll
        for (int i = 0; i < 4; ++i)
            a[i] = *(const frag_ab*)(As + (wr * 64 + i * 16 + l15) * 32 + quad * 8);
#pragma unroll
        for (int j = 0; j < 4; ++j)
            b[j] = *(const frag_ab*)(Bs + (wc * 64 + j * 16 + l15) * 32 + quad * 8);
#pragma unroll
        for (int i = 0; i < 4; ++i)
#pragma unroll
            for (int j = 0; j < 4; ++j)
                acc[i][j] = __builtin_amdgcn_mfma_f32_16x16x32_bf16(a[i], b[j], acc[i][j], 0, 0, 0);
    }

#pragma unroll
    for (int i = 0; i < 4; ++i)
#pragma unroll
        for (int r = 0; r < 4; ++r) {
            int row = row0 + wr * 64 + i * 16 + quad * 4 + r;
            if (row < N)
#pragma unroll
                for (int j = 0; j < 4; ++j) {
                    int col = wc * 64 + j * 16 + l15;
                    out[(size_t)row * 128 + col] = f2bf(acc[i][j][r] + bias[col]);
                }
        }
}

// ---------------- helpers ----------------
__device__ __forceinline__ void acc8(float* acc, uint4 v) {
    acc[0] += bf2f((ushort)(v.x & 0xffff)); acc[1] += bf2f((ushort)(v.x >> 16));
    acc[2] += bf2f((ushort)(v.y & 0xffff)); acc[3] += bf2f((ushort)(v.y >> 16));
    acc[4] += bf2f((ushort)(v.z & 0xffff)); acc[5] += bf2f((ushort)(v.z >> 16));
    acc[6] += bf2f((ushort)(v.w & 0xffff)); acc[7] += bf2f((ushort)(v.w >> 16));
}

// ---------------- fused: ELL mean-aggregate + dual GEMM (round-1 28KB layout) -----------
// Ms 16KB + As 4KB + Bs 8KB = 28KB -> 5 blocks/CU (20 waves) for the latency-bound
// gather (round 5 proved 52KB/3-block variant regresses: occupancy 17.7%, 64us).
// Experiment this round: 8 outstanding neighbor-row loads per lane (was 4).
template <bool RELU>
__global__ __launch_bounds__(256) void agg_gemm(
    const ushort* __restrict__ h, const ushort* __restrict__ ell,
    const int* __restrict__ degs,
    const ushort* __restrict__ Wtl, const ushort* __restrict__ Wtr,
    const float* __restrict__ bias, ushort* __restrict__ out, int N)
{
    __shared__ ushort Ms[64 * 128];   // chunk c of row r stored at c ^ (r&7)
    __shared__ ushort As[64 * 32];    // chunk swizzle kq ^ (r&3)
    __shared__ ushort Bs[128 * 32];   // chunk swizzle bk ^ (br&3)
    const int tid = threadIdx.x;
    const int lane = tid & 63;
    const int wave = tid >> 6;
    const int row0 = blockIdx.x * 64;
    const int g = lane >> 4;
    const int q = lane & 15;

    // ---- phase 1: mean aggregation into Ms (8-deep neighbor ILP) ----
#pragma unroll 1
    for (int it = 0; it < 4; ++it) {
        int r = (wave << 4) + (it << 2) + g;
        int node = row0 + r;
        int nd = node < N ? node : N - 1;
        const ushort* erow = ell + (size_t)nd * ELLW;
        int d = degs[nd << 4];
        int dc = d < ELLW ? d : ELLW;
        float acc[8];
#pragma unroll
        for (int k = 0; k < 8; ++k) acc[k] = 0.f;
        int n = 0;
        for (; n + 8 <= dc; n += 8) {
            ushort4 iv0 = *(const ushort4*)(erow + n);
            ushort4 iv1 = *(const ushort4*)(erow + n + 4);
            uint4 v0 = *(const uint4*)(h + (size_t)iv0.x * CH + q * 8);
            uint4 v1 = *(const uint4*)(h + (size_t)iv0.y * CH + q * 8);
            uint4 v2 = *(const uint4*)(h + (size_t)iv0.z * CH + q * 8);
            uint4 v3 = *(const uint4*)(h + (size_t)iv0.w * CH + q * 8);
            uint4 v4 = *(const uint4*)(h + (size_t)iv1.x * CH + q * 8);
            uint4 v5 = *(const uint4*)(h + (size_t)iv1.y * CH + q * 8);
            uint4 v6 = *(const uint4*)(h + (size_t)iv1.z * CH + q * 8);
            uint4 v7 = *(const uint4*)(h + (size_t)iv1.w * CH + q * 8);
            acc8(acc, v0); acc8(acc, v1); acc8(acc, v2); acc8(acc, v3);
            acc8(acc, v4); acc8(acc, v5); acc8(acc, v6); acc8(acc, v7);
        }
        for (; n + 4 <= dc; n += 4) {
            ushort4 iv = *(const ushort4*)(erow + n);
            uint4 v0 = *(const uint4*)(h + (size_t)iv.x * CH + q * 8);
            uint4 v1 = *(const uint4*)(h + (size_t)iv.y * CH + q * 8);
            uint4 v2 = *(const uint4*)(h + (size_t)iv.z * CH + q * 8);
            uint4 v3 = *(const uint4*)(h + (size_t)iv.w * CH + q * 8);
            acc8(acc, v0); acc8(acc, v1); acc8(acc, v2); acc8(acc, v3);
        }
        for (; n < dc; ++n) {
            uint4 v0 = *(const uint4*)(h + (size_t)erow[n] * CH + q * 8);
            acc8(acc, v0);
        }
        float inv = 1.f / fmaxf((float)d, 1.f);
        uint4 o;
        o.x = ((uint)f2bf(acc[1] * inv) << 16) | (uint)f2bf(acc[0] * inv);
        o.y = ((uint)f2bf(acc[3] * inv) << 16) | (uint)f2bf(acc[2] * inv);
        o.z = ((uint)f2bf(acc[5] * inv) << 16) | (uint)f2bf(acc[4] * inv);
        o.w = ((uint)f2bf(acc[7] * inv) << 16) | (uint)f2bf(acc[6] * inv);
        int chunk = q ^ (r & 7);
        *(uint4*)(Ms + r * 128 + chunk * 8) = o;
    }

    // ---- phase 2: dual GEMM ----
    const int wr = wave >> 1, wc = wave & 1;
    const int l15 = q, quad = g;

    frag_cd acc2[2][4];
#pragma unroll
    for (int i = 0; i < 2; ++i)
#pragma unroll
        for (int j = 0; j < 4; ++j) acc2[i][j] = (frag_cd){0.f, 0.f, 0.f, 0.f};

#pragma unroll 1
    for (int part = 0; part < 2; ++part) {
        const ushort* Wt = part ? Wtr : Wtl;
#pragma unroll 1
        for (int k0 = 0; k0 < 128; k0 += 32) {
            __syncthreads();   // first pass also orders Ms writes before Ms reads
            if (part) {
                int rr = tid >> 2, kq = tid & 3;
                int gr = row0 + rr; if (gr > N - 1) gr = N - 1;
                uint4 v = *(const uint4*)(h + (size_t)gr * CH + k0 + kq * 8);
                *(uint4*)(As + rr * 32 + ((kq ^ (rr & 3)) * 8)) = v;
            }
#pragma unroll
            for (int i2 = 0; i2 < 2; ++i2) {
                int e = i2 * 256 + tid;
                int br = e >> 2, bk = e & 3;
                uint4 v = *(const uint4*)(Wt + (size_t)br * 128 + k0 + bk * 8);
                *(uint4*)(Bs + br * 32 + ((bk ^ (br & 3)) * 8)) = v;
            }
            __syncthreads();

            frag_ab a[2], b[4];
#pragma unroll
            for (int i = 0; i < 2; ++i) {
                int ar = wr * 32 + i * 16 + l15;
                if (part) {
                    a[i] = *(const frag_ab*)(As + ar * 32 + ((quad ^ (ar & 3)) * 8));
                } else {
                    int ch = ((k0 >> 3) + quad) ^ (ar & 7);
                    a[i] = *(const frag_ab*)(Ms + ar * 128 + ch * 8);
                }
            }
#pragma unroll
            for (int j = 0; j < 4; ++j) {
                int br = wc * 64 + j * 16 + l15;
                b[j] = *(const frag_ab*)(Bs + br * 32 + ((quad ^ (br & 3)) * 8));
            }
#pragma unroll
            for (int i = 0; i < 2; ++i)
#pragma unroll
                for (int j = 0; j < 4; ++j)
                    acc2[i][j] = __builtin_amdgcn_mfma_f32_16x16x32_bf16(a[i], b[j], acc2[i][j], 0, 0, 0);
        }
    }

#pragma unroll
    for (int i = 0; i < 2; ++i)
#pragma unroll
        for (int rr = 0; rr < 4; ++rr) {
            int row = row0 + wr * 32 + i * 16 + quad * 4 + rr;
            if (row < N)
#pragma unroll
                for (int j = 0; j < 4; ++j) {
                    int col = wc * 64 + j * 16 + l15;
                    float v = acc2[i][j][rr] + bias[col];
                    if (RELU) v = fmaxf(v, 0.f);
                    out[(size_t)row * 128 + col] = f2bf(v);
                }
        }
}

// ---------------- classifier: 8 edges / 16-lane group ----------------
__device__ __forceinline__ float dot8(uint4 va, uint4 vb) {
    float p = 0.f;
    p += bf2f((ushort)(va.x & 0xffff)) * bf2f((ushort)(vb.x & 0xffff));
    p += bf2f((ushort)(va.x >> 16))    * bf2f((ushort)(vb.x >> 16));
    p += bf2f((ushort)(va.y & 0xffff)) * bf2f((ushort)(vb.y & 0xffff));
    p += bf2f((ushort)(va.y >> 16))    * bf2f((ushort)(vb.y >> 16));
    p += bf2f((ushort)(va.z & 0xffff)) * bf2f((ushort)(vb.z & 0xffff));
    p += bf2f((ushort)(va.z >> 16))    * bf2f((ushort)(vb.z >> 16));
    p += bf2f((ushort)(va.w & 0xffff)) * bf2f((ushort)(vb.w & 0xffff));
    p += bf2f((ushort)(va.w >> 16))    * bf2f((ushort)(vb.w >> 16));
    return p;
}

__global__ __launch_bounds__(256) void classify_bf(
    const ushort* __restrict__ h2, const int* __restrict__ eli,
    int EL, float* __restrict__ out) {
    int gt = blockIdx.x * blockDim.x + threadIdx.x;
    int g0 = (gt >> 4) * 8;
    int lane = gt & 15;
    if (g0 >= EL) return;
    bool full = (g0 + 7 < EL);
    int ha[8], ta[8];
    if (full) {
        int4 h0 = *(const int4*)(eli + g0);
        int4 h1 = *(const int4*)(eli + g0 + 4);
        int4 t0 = *(const int4*)(eli + EL + g0);
        int4 t1 = *(const int4*)(eli + EL + g0 + 4);
        ha[0] = h0.x; ha[1] = h0.y; ha[2] = h0.z; ha[3] = h0.w;
        ha[4] = h1.x; ha[5] = h1.y; ha[6] = h1.z; ha[7] = h1.w;
        ta[0] = t0.x; ta[1] = t0.y; ta[2] = t0.z; ta[3] = t0.w;
        ta[4] = t1.x; ta[5] = t1.y; ta[6] = t1.z; ta[7] = t1.w;
    } else {
#pragma unroll
        for (int j = 0; j < 8; ++j) {
            int gj = (g0 + j < EL) ? g0 + j : EL - 1;
            ha[j] = eli[gj];
            ta[j] = eli[EL + gj];
        }
    }
    uint4 va[8], vb[8];
#pragma unroll
    for (int j = 0; j < 8; ++j) {
        va[j] = *((const uint4*)(h2 + (size_t)ha[j] * CH) + lane);
        vb[j] = *((const uint4*)(h2 + (size_t)ta[j] * CH) + lane);
    }
    float p[8];
#pragma unroll
    for (int j = 0; j < 8; ++j) p[j] = dot8(va[j], vb[j]);
#pragma unroll
    for (int s = 8; s >= 1; s >>= 1) {
#pragma unroll
        for (int j = 0; j < 8; ++j) p[j] += __shfl_down(p[j], s, 16);
    }
    if (lane == 0) {
        if (full) {
            *(float4*)(out + g0)     = make_float4(p[0], p[1], p[2], p[3]);
            *(float4*)(out + g0 + 4) = make_float4(p[4], p[5], p[6], p[7]);
        } else {
#pragma unroll
            for (int j = 0; j < 8; ++j)
                if (g0 + j < EL) out[g0 + j] = p[j];
        }
    }
}

extern "C" void kernel_launch(void* const* d_in, const int* in_sizes, int n_in,
                              void* d_out, int out_size, void* d_ws, size_t ws_size,
                              hipStream_t stream) {
    const float* x     = (const float*)d_in[0];
    const int*   ei    = (const int*)d_in[1];
    const int*   eli   = (const int*)d_in[2];
    const float* W_lin = (const float*)d_in[3];
    const float* b_lin = (const float*)d_in[4];
    const float* W1l   = (const float*)d_in[5];
    const float* b1    = (const float*)d_in[6];
    const float* W1r   = (const float*)d_in[7];
    const float* W2l   = (const float*)d_in[8];
    const float* b2    = (const float*)d_in[9];
    const float* W2r   = (const float*)d_in[10];
    float* out = (float*)d_out;

    const int E  = in_sizes[1] / 2;
    const int EL = in_sizes[2] / 2;
    const int N  = NODES;

    char* ws = (char*)d_ws;
    size_t off = 0;
    auto alloc = [&](size_t bytes) -> void* {
        void* p = ws + off;
        off += (bytes + 255) & ~(size_t)255;
        return p;
    };
    ushort* n0    = (ushort*)alloc((size_t)N * CH * sizeof(ushort));  // h0
    ushort* n1    = (ushort*)alloc((size_t)N * CH * sizeof(ushort));  // h2
    ushort* n2    = (ushort*)alloc((size_t)N * CH * sizeof(ushort));  // h1
    ushort* WtLin = (ushort*)alloc((size_t)CH * 384 * sizeof(ushort));
    ushort* Wt1l  = (ushort*)alloc((size_t)CH * CH * sizeof(ushort));
    ushort* Wt1r  = (ushort*)alloc((size_t)CH * CH * sizeof(ushort));
    ushort* Wt2l  = (ushort*)alloc((size_t)CH * CH * sizeof(ushort));
    ushort* Wt2r  = (ushort*)alloc((size_t)CH * CH * sizeof(ushort));
    int* degs = (int*)alloc((size_t)N * 16 * sizeof(int));  // stride-16: 1 counter / 64B line
    ushort* ell = (ushort*)alloc((size_t)N * ELLW * sizeof(ushort));
    (void)ws_size; (void)n_in; (void)out_size;

    const int GB128 = (N + 127) / 128;          // 391 gemm tiles
    const int EB4   = (E + 1023) / 1024;        // 782 fill blocks (256 thr x 4 edges)
    const int AB64  = (N + 63) / 64;            // 782 fused agg_gemm blocks

    // 1) weight transposes + deg zeroing
    prep_weights<<<dim3(644), dim3(128, 2), 0, stream>>>(
        W_lin, W1l, W1r, W2l, W2r, WtLin, Wt1l, Wt1r, Wt2l, Wt2r, degs);

    // 2) h0 = bf16(x)@W_lin + b_lin  OVERLAPPED WITH  ELL build
    lin_and_ell<<<dim3(GB128 + EB4), dim3(256), 0, stream>>>(
        x, WtLin, b_lin, n0, N, GB128, ei, E, degs, ell);

    // 3) layer 1 fused: h1 = relu(mean(h0)@W1l + h0@W1r + b1) -> n2
    agg_gemm<true><<<dim3(AB64), dim3(256), 0, stream>>>(
        n0, ell, degs, Wt1l, Wt1r, b1, n2, N);

    // 4) layer 2 fused: h2 = mean(h1)@W2l + h1@W2r + b2 -> n1
    agg_gemm<false><<<dim3(AB64), dim3(256), 0, stream>>>(
        n2, ell, degs, Wt2l, Wt2r, b2, n1, N);

    // 5) classifier on h2 = n1
    long long groups = ((long long)EL + 7) / 8;
    long long cls_threads = groups * 16;
    classify_bf<<<dim3((int)((cls_threads + 255) / 256)), dim3(256), 0, stream>>>(
        n1, eli, EL, out);
}